// Round 7
// baseline (174.666 us; speedup 1.0000x reference)
//
#include <hip/hip_runtime.h>

// Problem constants (from reference setup_inputs): bs=4, p=262144, c=32, h=w=512
#define BS 4
#define P  262144      // 2^18
#define C  32
#define H  512
#define W  512
#define HW (H * W)     // 262144 = 2^18
#define NEPS 1e-8f

// d_out layout (all float32, concatenated):
//   out : BS*C*HW, conf: BS*HW, viz: BS*P
//
// Fast path accumulator: acc2[b][pix] = 128B record (32 dwords):
//   dw 0..15  : 32 channels as pk-bf16 pairs (atomic pk_add_bf16)
//   dw 16     : conf as f32 (atomic f32 add) -- folded into the SAME line,
//               so each point makes exactly ONE L2 line-visit (17 dwords)
//   dw 17..31 : pad (never read)
// Measured model (r2/r4/r6): scatter time = per-line-visit fixed cost (~60%)
// + per-dword RMW cost; staging is fully hidden under atomic backpressure.

#define TP 64          // points per block in scatter

__device__ inline void pk_add_bf16(unsigned short* p, unsigned int v)
{
    // global_atomic_pk_add_bf16: adds 2 bf16 lanes to memory, no return.
    asm volatile("global_atomic_pk_add_bf16 %0, %1, off"
                 :: "v"(p), "v"(v) : "memory");
}

// pack two floats into 2 bf16 with round-nearest-even (finite inputs only)
__device__ inline unsigned int pack_bf16_rne(float a, float b)
{
    unsigned int ua = __builtin_bit_cast(unsigned int, a);
    unsigned int ub = __builtin_bit_cast(unsigned int, b);
    ua += 0x7FFFu + ((ua >> 16) & 1u);
    ub += 0x7FFFu + ((ub >> 16) & 1u);
    return (ua >> 16) | (ub & 0xFFFF0000u);
}
__device__ inline float bf16_lo(unsigned int w) { return __builtin_bit_cast(float, w << 16); }
__device__ inline float bf16_hi(unsigned int w) { return __builtin_bit_cast(float, w & 0xFFFF0000u); }

__global__ __launch_bounds__(256) void splat_scatter_t(
    const float* __restrict__ xyz, const float* __restrict__ data,
    unsigned int* __restrict__ acc2, float* __restrict__ viz)
{
    __shared__ float s_feat[C][TP + 1];   // +1 pad: transposed read conflict-free
    __shared__ float s_xyz[TP * 3];
    __shared__ float s_wgt[TP];
    __shared__ int   s_pix[TP];

    const int t    = threadIdx.x;
    const int base = blockIdx.x * TP;
    const int b    = base >> 18;            // P = 2^18
    const int j0   = base & (P - 1);

    // ---- stage features: data[b][ch][j0..j0+63] for all 32 ch (coalesced float4)
    const float4* dsrc = (const float4*)(data + (size_t)b * C * P + j0);
    #pragma unroll
    for (int i = 0; i < 2; ++i) {
        int f4 = i * 256 + t;                // 0..511
        int ch = f4 >> 4;                    // 16 float4 per channel row
        int q  = f4 & 15;
        float4 v = dsrc[(size_t)ch * (P / 4) + q];
        s_feat[ch][q * 4 + 0] = v.x;
        s_feat[ch][q * 4 + 1] = v.y;
        s_feat[ch][q * 4 + 2] = v.z;
        s_feat[ch][q * 4 + 3] = v.w;
    }
    // ---- stage xyz: 192 contiguous floats (48 float4)
    if (t < 48) {
        float4 v = ((const float4*)(xyz + (size_t)base * 3))[t];
        s_xyz[t * 4 + 0] = v.x;
        s_xyz[t * 4 + 1] = v.y;
        s_xyz[t * 4 + 2] = v.z;
        s_xyz[t * 4 + 3] = v.w;
    }
    __syncthreads();

    // ---- per-point geometry (threads 0..63); NO separate conf atomic anymore
    if (t < TP) {
        float x = s_xyz[3 * t + 0];
        float y = s_xyz[3 * t + 1];
        float z = s_xyz[3 * t + 2];
        float px = (x + 1.0f) * 0.5f * (float)(W - 1);
        float py = (y + 1.0f) * 0.5f * (float)(H - 1);
        bool v = (px > -0.5f) && (px < (float)W - 0.5f) &&
                 (py > -0.5f) && (py < (float)H - 0.5f) && (z > 0.0f);
        viz[base + t] = v ? 1.0f : 0.0f;
        int pix = -1;
        float wg = 0.0f;
        if (v) {
            int xi = (int)fminf(fmaxf(rintf(px), 0.0f), (float)(W - 1));
            int yi = (int)fminf(fmaxf(rintf(py), 0.0f), (float)(H - 1));
            pix = yi * W + xi;
            wg  = 1.0f / fmaxf(z, NEPS);
        }
        s_pix[t] = pix;
        s_wgt[t] = wg;
    }
    __syncthreads();

    // ---- one-line-visit atomics: 16 lanes per point; lane d -> ch 2d,2d+1;
    //      lane 0 additionally adds conf into dword 16 of the SAME record.
    const int g = t >> 4;      // 0..15 point subgroup
    const int d = t & 15;      // pair index within record
    #pragma unroll
    for (int k = 0; k < TP / 16; ++k) {
        int jj  = k * 16 + g;
        int pix = s_pix[jj];                 // LDS broadcast
        if (pix >= 0) {
            float wg = s_wgt[jj];
            size_t rec_dw = (((size_t)b << 18) + pix) * 32;   // dword index of record
            pk_add_bf16((unsigned short*)acc2 + rec_dw * 2 + 2 * d,
                        pack_bf16_rne(s_feat[2 * d + 0][jj] * wg,
                                      s_feat[2 * d + 1][jj] * wg));
            if (d == 0)
                unsafeAtomicAdd((float*)acc2 + rec_dw + 16, wg);
        }
    }
}

__global__ __launch_bounds__(256) void splat_transpose_norm(
    const unsigned int* __restrict__ acc2,
    float* __restrict__ out, float* __restrict__ conf_out)
{
    __shared__ float s_t[64][C + 1];
    __shared__ float s_inv[64];

    const int t    = threadIdx.x;
    const int blk  = blockIdx.x;             // over BS*HW/64
    const int b    = blk >> 12;              // HW/64 = 2^12 blocks per batch
    const int pix0 = (blk & ((HW / 64) - 1)) * 64;

    const unsigned int* rb = acc2 + ((size_t)b * HW + pix0) * 32;

    // conf: dword 16 of each record; write out + build inv
    if (t < 64) {
        float cf = __builtin_bit_cast(float, rb[(size_t)t * 32 + 16]);
        conf_out[(size_t)b * HW + pix0 + t] = cf;
        s_inv[t] = 1.0f / fmaxf(cf, NEPS);
    }

    // features: 4 threads per pixel, uint4 each (dwords 0..15 of record)
    {
        int po = t >> 2;                     // pixel within tile
        int q  = t & 3;
        uint4 v = *(const uint4*)(rb + (size_t)po * 32 + q * 4);
        int ch0 = q * 8;
        unsigned int ws[4] = {v.x, v.y, v.z, v.w};
        #pragma unroll
        for (int w = 0; w < 4; ++w) {
            s_t[po][ch0 + 2 * w + 0] = bf16_lo(ws[w]);
            s_t[po][ch0 + 2 * w + 1] = bf16_hi(ws[w]);
        }
    }
    __syncthreads();

    #pragma unroll
    for (int i = 0; i < 8; ++i) {
        int e  = i * 256 + t;                // 0..2047
        int ch = e >> 6;
        int po = e & 63;
        out[((size_t)b * C + ch) * HW + pix0 + po] = s_t[po][ch] * s_inv[po];
    }
}

// ---------------- fallback: direct f32 atomics into d_out (no ws needed) ------

__global__ __launch_bounds__(256) void splat_scatter_fb(
    const float* __restrict__ xyz, const float* __restrict__ data,
    float* __restrict__ acc, float* __restrict__ conf, float* __restrict__ viz)
{
    int idx = blockIdx.x * 256 + threadIdx.x;
    if (idx >= BS * P) return;
    int b = idx >> 18;
    int j = idx & (P - 1);
    float x = xyz[3 * idx + 0], y = xyz[3 * idx + 1], z = xyz[3 * idx + 2];
    float px = (x + 1.0f) * 0.5f * (float)(W - 1);
    float py = (y + 1.0f) * 0.5f * (float)(H - 1);
    bool v = (px > -0.5f) && (px < (float)W - 0.5f) &&
             (py > -0.5f) && (py < (float)H - 0.5f) && (z > 0.0f);
    viz[idx] = v ? 1.0f : 0.0f;
    if (!v) return;
    int xi = (int)fminf(fmaxf(rintf(px), 0.0f), (float)(W - 1));
    int yi = (int)fminf(fmaxf(rintf(py), 0.0f), (float)(H - 1));
    float wg = 1.0f / fmaxf(z, NEPS);
    int pix = yi * W + xi;
    unsafeAtomicAdd(&conf[b * HW + pix], wg);
    const float* db = data + (size_t)b * C * P + j;
    float*       ab = acc  + (size_t)b * C * HW + pix;
    #pragma unroll
    for (int ch = 0; ch < C; ++ch)
        unsafeAtomicAdd(ab + (size_t)ch * HW, db[(size_t)ch * P] * wg);
}

__global__ __launch_bounds__(256) void splat_norm_fb(
    float* __restrict__ out, const float* __restrict__ conf)
{
    int idx = blockIdx.x * 256 + threadIdx.x;
    if (idx >= BS * HW) return;
    int b   = idx >> 18;
    int pix = idx & (HW - 1);
    float inv = 1.0f / fmaxf(conf[idx], NEPS);
    float* ob = out + (size_t)b * C * HW + pix;
    #pragma unroll
    for (int ch = 0; ch < C; ++ch)
        ob[(size_t)ch * HW] *= inv;
}

extern "C" void kernel_launch(void* const* d_in, const int* in_sizes, int n_in,
                              void* d_out, int out_size, void* d_ws, size_t ws_size,
                              hipStream_t stream)
{
    const float* xyz  = (const float*)d_in[0];   // (BS, P, 3)
    const float* data = (const float*)d_in[1];   // (BS, C, P)

    float* out  = (float*)d_out;
    float* conf = out  + (size_t)BS * C * HW;
    float* viz  = conf + (size_t)BS * HW;

    const size_t acc2_bytes = (size_t)BS * HW * 128;   // 128 MiB (fit proven in r2)

    if (ws_size >= acc2_bytes) {
        unsigned int* acc2 = (unsigned int*)d_ws;
        (void)hipMemsetAsync(acc2, 0, acc2_bytes, stream);
        splat_scatter_t<<<BS * P / TP, 256, 0, stream>>>(xyz, data, acc2, viz);
        splat_transpose_norm<<<BS * HW / 64, 256, 0, stream>>>(acc2, out, conf);
    } else {
        (void)hipMemsetAsync(d_out, 0, (size_t)(BS * C * HW + BS * HW) * sizeof(float), stream);
        splat_scatter_fb<<<(BS * P + 255) / 256, 256, 0, stream>>>(xyz, data, out, conf, viz);
        splat_norm_fb<<<(BS * HW + 255) / 256, 256, 0, stream>>>(out, conf);
    }
}

// Round 8
// 157.208 us; speedup vs baseline: 1.1110x; 1.1110x over previous
//
#include <hip/hip_runtime.h>

// Problem constants (from reference setup_inputs): bs=4, p=262144, c=32, h=w=512
#define BS 4
#define P  262144      // 2^18
#define C  32
#define H  512
#define W  512
#define HW (H * W)     // 262144 = 2^18
#define NEPS 1e-8f

// d_out layout (all float32, concatenated):
//   out : BS*C*HW, conf: BS*HW, viz: BS*P
//
// Fast path: acc_bf[b][pix][ch] bf16 (64B records) in d_ws; scatter uses
// packed-bf16 atomics (2 ch per dword-RMW). Measured (r4/r6/r7): scatter is
// pinned at ~110us by the device atomic machinery for ~16M dword-RMWs --
// staging shape, line-visit count, and conf placement all measured neutral.
// This round only rebuilds the transpose (256-px tiles, 1KiB/ch contiguous
// writes) to close its ~8us gap to the write roofline.

#define TP 64          // points per block in scatter
#define XP 256         // pixels per block in transpose

__device__ inline void pk_add_bf16(unsigned short* p, unsigned int v)
{
    // global_atomic_pk_add_bf16: adds 2 bf16 lanes to memory, no return.
    asm volatile("global_atomic_pk_add_bf16 %0, %1, off"
                 :: "v"(p), "v"(v) : "memory");
}

// pack two floats into 2 bf16 with round-nearest-even (finite inputs only)
__device__ inline unsigned int pack_bf16_rne(float a, float b)
{
    unsigned int ua = __builtin_bit_cast(unsigned int, a);
    unsigned int ub = __builtin_bit_cast(unsigned int, b);
    ua += 0x7FFFu + ((ua >> 16) & 1u);
    ub += 0x7FFFu + ((ub >> 16) & 1u);
    return (ua >> 16) | (ub & 0xFFFF0000u);
}
__device__ inline float bf16_lo(unsigned int w) { return __builtin_bit_cast(float, w << 16); }
__device__ inline float bf16_hi(unsigned int w) { return __builtin_bit_cast(float, w & 0xFFFF0000u); }

__global__ __launch_bounds__(256) void splat_scatter_t(
    const float* __restrict__ xyz, const float* __restrict__ data,
    unsigned short* __restrict__ acc, float* __restrict__ conf,
    float* __restrict__ viz)
{
    __shared__ float s_feat[C][TP + 1];   // +1 pad: transposed read conflict-free
    __shared__ float s_xyz[TP * 3];
    __shared__ float s_wgt[TP];
    __shared__ int   s_pix[TP];

    const int t    = threadIdx.x;
    const int base = blockIdx.x * TP;
    const int b    = base >> 18;            // P = 2^18
    const int j0   = base & (P - 1);

    // ---- stage features: data[b][ch][j0..j0+63] for all 32 ch (coalesced float4)
    const float4* dsrc = (const float4*)(data + (size_t)b * C * P + j0);
    #pragma unroll
    for (int i = 0; i < 2; ++i) {
        int f4 = i * 256 + t;                // 0..511
        int ch = f4 >> 4;                    // 16 float4 per channel row
        int q  = f4 & 15;
        float4 v = dsrc[(size_t)ch * (P / 4) + q];
        s_feat[ch][q * 4 + 0] = v.x;
        s_feat[ch][q * 4 + 1] = v.y;
        s_feat[ch][q * 4 + 2] = v.z;
        s_feat[ch][q * 4 + 3] = v.w;
    }
    // ---- stage xyz: 192 contiguous floats (48 float4)
    if (t < 48) {
        float4 v = ((const float4*)(xyz + (size_t)base * 3))[t];
        s_xyz[t * 4 + 0] = v.x;
        s_xyz[t * 4 + 1] = v.y;
        s_xyz[t * 4 + 2] = v.z;
        s_xyz[t * 4 + 3] = v.w;
    }
    __syncthreads();

    // ---- per-point geometry (threads 0..63)
    if (t < TP) {
        float x = s_xyz[3 * t + 0];
        float y = s_xyz[3 * t + 1];
        float z = s_xyz[3 * t + 2];
        float px = (x + 1.0f) * 0.5f * (float)(W - 1);
        float py = (y + 1.0f) * 0.5f * (float)(H - 1);
        bool v = (px > -0.5f) && (px < (float)W - 0.5f) &&
                 (py > -0.5f) && (py < (float)H - 0.5f) && (z > 0.0f);
        viz[base + t] = v ? 1.0f : 0.0f;
        int pix = -1;
        float wg = 0.0f;
        if (v) {
            int xi = (int)fminf(fmaxf(rintf(px), 0.0f), (float)(W - 1));
            int yi = (int)fminf(fmaxf(rintf(py), 0.0f), (float)(H - 1));
            pix = yi * W + xi;
            wg  = 1.0f / fmaxf(z, NEPS);
            unsafeAtomicAdd(&conf[b * HW + pix], wg);
        }
        s_pix[t] = pix;
        s_wgt[t] = wg;
    }
    __syncthreads();

    // ---- packed-bf16 atomics: 16 lanes per point (lane d -> channels 2d,2d+1)
    const int g = t >> 4;      // 0..15 point subgroup
    const int d = t & 15;      // pair index
    #pragma unroll
    for (int k = 0; k < TP / 16; ++k) {
        int jj  = k * 16 + g;
        int pix = s_pix[jj];                 // LDS broadcast
        if (pix >= 0) {
            float wg = s_wgt[jj];
            pk_add_bf16(acc + (((size_t)b << 18) + pix) * C + 2 * d,
                        pack_bf16_rne(s_feat[2 * d + 0][jj] * wg,
                                      s_feat[2 * d + 1][jj] * wg));
        }
    }
}

__global__ __launch_bounds__(256) void splat_transpose_norm(
    const unsigned short* __restrict__ acc, const float* __restrict__ conf,
    float* __restrict__ out)
{
    __shared__ float s_t[XP][C + 1];      // [256][33]: read banks (t+i)%32 CF
    __shared__ float s_inv[XP];

    const int t    = threadIdx.x;
    const int blk  = blockIdx.x;             // over BS*HW/XP = 4096
    const int b    = blk >> 10;              // HW/XP = 2^10 blocks per batch
    const int pix0 = (blk & ((HW / XP) - 1)) * XP;

    s_inv[t] = 1.0f / fmaxf(conf[(size_t)b * HW + pix0 + t], NEPS);

    // read: 256 px x 32 ch bf16 = 16KB contiguous; 4 uint4 per thread
    const uint4* src = (const uint4*)(acc + ((size_t)b * HW + pix0) * C);
    #pragma unroll
    for (int i = 0; i < 4; ++i) {
        int e = i * 256 + t;                  // uint4 index 0..1023
        uint4 v = src[e];
        int po  = e >> 2;
        int ch0 = (e & 3) * 8;
        unsigned int ws[4] = {v.x, v.y, v.z, v.w};
        // LDS banks: (33*(t>>2) + 8*(t&3))%32 distinct over half-wave -> CF
        #pragma unroll
        for (int w = 0; w < 4; ++w) {
            s_t[po][ch0 + 2 * w + 0] = bf16_lo(ws[w]);
            s_t[po][ch0 + 2 * w + 1] = bf16_hi(ws[w]);
        }
    }
    __syncthreads();

    // write: iter i = channel i; block writes 1KiB contiguous per channel
    size_t ob = (size_t)b * C * HW + pix0;
    #pragma unroll
    for (int ch = 0; ch < C; ++ch)
        out[ob + (size_t)ch * HW + t] = s_t[t][ch] * s_inv[t];
}

// ---------------- fallback: direct f32 atomics into d_out (no ws needed) ------

__global__ __launch_bounds__(256) void splat_scatter_fb(
    const float* __restrict__ xyz, const float* __restrict__ data,
    float* __restrict__ acc, float* __restrict__ conf, float* __restrict__ viz)
{
    int idx = blockIdx.x * 256 + threadIdx.x;
    if (idx >= BS * P) return;
    int b = idx >> 18;
    int j = idx & (P - 1);
    float x = xyz[3 * idx + 0], y = xyz[3 * idx + 1], z = xyz[3 * idx + 2];
    float px = (x + 1.0f) * 0.5f * (float)(W - 1);
    float py = (y + 1.0f) * 0.5f * (float)(H - 1);
    bool v = (px > -0.5f) && (px < (float)W - 0.5f) &&
             (py > -0.5f) && (py < (float)H - 0.5f) && (z > 0.0f);
    viz[idx] = v ? 1.0f : 0.0f;
    if (!v) return;
    int xi = (int)fminf(fmaxf(rintf(px), 0.0f), (float)(W - 1));
    int yi = (int)fminf(fmaxf(rintf(py), 0.0f), (float)(H - 1));
    float wg = 1.0f / fmaxf(z, NEPS);
    int pix = yi * W + xi;
    unsafeAtomicAdd(&conf[b * HW + pix], wg);
    const float* db = data + (size_t)b * C * P + j;
    float*       ab = acc  + (size_t)b * C * HW + pix;
    #pragma unroll
    for (int ch = 0; ch < C; ++ch)
        unsafeAtomicAdd(ab + (size_t)ch * HW, db[(size_t)ch * P] * wg);
}

__global__ __launch_bounds__(256) void splat_norm_fb(
    float* __restrict__ out, const float* __restrict__ conf)
{
    int idx = blockIdx.x * 256 + threadIdx.x;
    if (idx >= BS * HW) return;
    int b   = idx >> 18;
    int pix = idx & (HW - 1);
    float inv = 1.0f / fmaxf(conf[idx], NEPS);
    float* ob = out + (size_t)b * C * HW + pix;
    #pragma unroll
    for (int ch = 0; ch < C; ++ch)
        ob[(size_t)ch * HW] *= inv;
}

extern "C" void kernel_launch(void* const* d_in, const int* in_sizes, int n_in,
                              void* d_out, int out_size, void* d_ws, size_t ws_size,
                              hipStream_t stream)
{
    const float* xyz  = (const float*)d_in[0];   // (BS, P, 3)
    const float* data = (const float*)d_in[1];   // (BS, C, P)

    float* out  = (float*)d_out;
    float* conf = out  + (size_t)BS * C * HW;
    float* viz  = conf + (size_t)BS * HW;

    const size_t acc_bytes = (size_t)BS * HW * C * sizeof(unsigned short);  // 64 MB

    if (ws_size >= acc_bytes) {
        unsigned short* acc = (unsigned short*)d_ws;
        (void)hipMemsetAsync(acc, 0, acc_bytes, stream);
        (void)hipMemsetAsync(conf, 0, (size_t)BS * HW * sizeof(float), stream);
        splat_scatter_t<<<BS * P / TP, 256, 0, stream>>>(xyz, data, acc, conf, viz);
        splat_transpose_norm<<<BS * HW / XP, 256, 0, stream>>>(acc, conf, out);
    } else {
        (void)hipMemsetAsync(d_out, 0, (size_t)(BS * C * HW + BS * HW) * sizeof(float), stream);
        splat_scatter_fb<<<(BS * P + 255) / 256, 256, 0, stream>>>(xyz, data, out, conf, viz);
        splat_norm_fb<<<(BS * HW + 255) / 256, 256, 0, stream>>>(out, conf);
    }
}

// Round 9
// 152.134 us; speedup vs baseline: 1.1481x; 1.0334x over previous
//
#include <hip/hip_runtime.h>

// Problem constants (from reference setup_inputs): bs=4, p=262144, c=32, h=w=512
#define BS 4
#define P  262144      // 2^18
#define C  32
#define H  512
#define W  512
#define HW (H * W)     // 262144 = 2^18
#define NEPS 1e-8f

// d_out layout (all float32, concatenated):
//   out : BS*C*HW, conf: BS*HW, viz: BS*P
//
// Fast path: acc_bf[b][pix][ch] bf16 (64B records) in d_ws; scatter uses
// packed-bf16 atomics (2 ch per dword-RMW). Measured floor (r4-r8): scatter
// ~110us = per-channel-serialized dword-RMW wall (15.2M RMWs, 1 line/point)
// + line-miss machinery; staging shape, line-visit count, conf placement,
// and transpose tiling all measured neutral. This is the r4 best config.

#define TP 64          // points per block in scatter

__device__ inline void pk_add_bf16(unsigned short* p, unsigned int v)
{
    // global_atomic_pk_add_bf16: adds 2 bf16 lanes to memory, no return.
    asm volatile("global_atomic_pk_add_bf16 %0, %1, off"
                 :: "v"(p), "v"(v) : "memory");
}

// pack two floats into 2 bf16 with round-nearest-even (finite inputs only)
__device__ inline unsigned int pack_bf16_rne(float a, float b)
{
    unsigned int ua = __builtin_bit_cast(unsigned int, a);
    unsigned int ub = __builtin_bit_cast(unsigned int, b);
    ua += 0x7FFFu + ((ua >> 16) & 1u);
    ub += 0x7FFFu + ((ub >> 16) & 1u);
    return (ua >> 16) | (ub & 0xFFFF0000u);
}
__device__ inline float bf16_lo(unsigned int w) { return __builtin_bit_cast(float, w << 16); }
__device__ inline float bf16_hi(unsigned int w) { return __builtin_bit_cast(float, w & 0xFFFF0000u); }

__global__ __launch_bounds__(256) void splat_scatter_t(
    const float* __restrict__ xyz, const float* __restrict__ data,
    unsigned short* __restrict__ acc, float* __restrict__ conf,
    float* __restrict__ viz)
{
    __shared__ float s_feat[C][TP + 1];   // +1 pad: transposed read conflict-free
    __shared__ float s_xyz[TP * 3];
    __shared__ float s_wgt[TP];
    __shared__ int   s_pix[TP];

    const int t    = threadIdx.x;
    const int base = blockIdx.x * TP;
    const int b    = base >> 18;            // P = 2^18
    const int j0   = base & (P - 1);

    // ---- stage features: data[b][ch][j0..j0+63] for all 32 ch (coalesced float4)
    const float4* dsrc = (const float4*)(data + (size_t)b * C * P + j0);
    #pragma unroll
    for (int i = 0; i < 2; ++i) {
        int f4 = i * 256 + t;                // 0..511
        int ch = f4 >> 4;                    // 16 float4 per channel row
        int q  = f4 & 15;
        float4 v = dsrc[(size_t)ch * (P / 4) + q];
        s_feat[ch][q * 4 + 0] = v.x;
        s_feat[ch][q * 4 + 1] = v.y;
        s_feat[ch][q * 4 + 2] = v.z;
        s_feat[ch][q * 4 + 3] = v.w;
    }
    // ---- stage xyz: 192 contiguous floats (48 float4)
    if (t < 48) {
        float4 v = ((const float4*)(xyz + (size_t)base * 3))[t];
        s_xyz[t * 4 + 0] = v.x;
        s_xyz[t * 4 + 1] = v.y;
        s_xyz[t * 4 + 2] = v.z;
        s_xyz[t * 4 + 3] = v.w;
    }
    __syncthreads();

    // ---- per-point geometry (threads 0..63)
    if (t < TP) {
        float x = s_xyz[3 * t + 0];
        float y = s_xyz[3 * t + 1];
        float z = s_xyz[3 * t + 2];
        float px = (x + 1.0f) * 0.5f * (float)(W - 1);
        float py = (y + 1.0f) * 0.5f * (float)(H - 1);
        bool v = (px > -0.5f) && (px < (float)W - 0.5f) &&
                 (py > -0.5f) && (py < (float)H - 0.5f) && (z > 0.0f);
        viz[base + t] = v ? 1.0f : 0.0f;
        int pix = -1;
        float wg = 0.0f;
        if (v) {
            int xi = (int)fminf(fmaxf(rintf(px), 0.0f), (float)(W - 1));
            int yi = (int)fminf(fmaxf(rintf(py), 0.0f), (float)(H - 1));
            pix = yi * W + xi;
            wg  = 1.0f / fmaxf(z, NEPS);
            unsafeAtomicAdd(&conf[b * HW + pix], wg);
        }
        s_pix[t] = pix;
        s_wgt[t] = wg;
    }
    __syncthreads();

    // ---- packed-bf16 atomics: 16 lanes per point (lane d -> channels 2d,2d+1)
    const int g = t >> 4;      // 0..15 point subgroup
    const int d = t & 15;      // pair index
    #pragma unroll
    for (int k = 0; k < TP / 16; ++k) {
        int jj  = k * 16 + g;
        int pix = s_pix[jj];                 // LDS broadcast
        if (pix >= 0) {
            float wg = s_wgt[jj];
            pk_add_bf16(acc + (((size_t)b << 18) + pix) * C + 2 * d,
                        pack_bf16_rne(s_feat[2 * d + 0][jj] * wg,
                                      s_feat[2 * d + 1][jj] * wg));
        }
    }
}

__global__ __launch_bounds__(256) void splat_transpose_norm(
    const unsigned short* __restrict__ acc, const float* __restrict__ conf,
    float* __restrict__ out)
{
    __shared__ float s_t[64][C + 1];
    __shared__ float s_inv[64];

    const int t    = threadIdx.x;
    const int blk  = blockIdx.x;             // over BS*HW/64
    const int b    = blk >> 12;              // HW/64 = 2^12 blocks per batch
    const int pix0 = (blk & ((HW / 64) - 1)) * 64;

    if (t < 64)
        s_inv[t] = 1.0f / fmaxf(conf[(size_t)b * HW + pix0 + t], NEPS);

    // tile: 64 pixels x 32 ch bf16 = 4KB contiguous; one uint4 (8 bf16) per thread
    const uint4* src = (const uint4*)(acc + ((size_t)b * HW + pix0) * C);
    {
        uint4 v = src[t];
        int po  = t >> 2;
        int ch0 = (t & 3) * 8;
        unsigned int ws[4] = {v.x, v.y, v.z, v.w};
        #pragma unroll
        for (int w = 0; w < 4; ++w) {
            s_t[po][ch0 + 2 * w + 0] = bf16_lo(ws[w]);
            s_t[po][ch0 + 2 * w + 1] = bf16_hi(ws[w]);
        }
    }
    __syncthreads();

    #pragma unroll
    for (int i = 0; i < 8; ++i) {
        int e  = i * 256 + t;                // 0..2047
        int ch = e >> 6;
        int po = e & 63;
        out[((size_t)b * C + ch) * HW + pix0 + po] = s_t[po][ch] * s_inv[po];
    }
}

// ---------------- fallback: direct f32 atomics into d_out (no ws needed) ------

__global__ __launch_bounds__(256) void splat_scatter_fb(
    const float* __restrict__ xyz, const float* __restrict__ data,
    float* __restrict__ acc, float* __restrict__ conf, float* __restrict__ viz)
{
    int idx = blockIdx.x * 256 + threadIdx.x;
    if (idx >= BS * P) return;
    int b = idx >> 18;
    int j = idx & (P - 1);
    float x = xyz[3 * idx + 0], y = xyz[3 * idx + 1], z = xyz[3 * idx + 2];
    float px = (x + 1.0f) * 0.5f * (float)(W - 1);
    float py = (y + 1.0f) * 0.5f * (float)(H - 1);
    bool v = (px > -0.5f) && (px < (float)W - 0.5f) &&
             (py > -0.5f) && (py < (float)H - 0.5f) && (z > 0.0f);
    viz[idx] = v ? 1.0f : 0.0f;
    if (!v) return;
    int xi = (int)fminf(fmaxf(rintf(px), 0.0f), (float)(W - 1));
    int yi = (int)fminf(fmaxf(rintf(py), 0.0f), (float)(H - 1));
    float wg = 1.0f / fmaxf(z, NEPS);
    int pix = yi * W + xi;
    unsafeAtomicAdd(&conf[b * HW + pix], wg);
    const float* db = data + (size_t)b * C * P + j;
    float*       ab = acc  + (size_t)b * C * HW + pix;
    #pragma unroll
    for (int ch = 0; ch < C; ++ch)
        unsafeAtomicAdd(ab + (size_t)ch * HW, db[(size_t)ch * P] * wg);
}

__global__ __launch_bounds__(256) void splat_norm_fb(
    float* __restrict__ out, const float* __restrict__ conf)
{
    int idx = blockIdx.x * 256 + threadIdx.x;
    if (idx >= BS * HW) return;
    int b   = idx >> 18;
    int pix = idx & (HW - 1);
    float inv = 1.0f / fmaxf(conf[idx], NEPS);
    float* ob = out + (size_t)b * C * HW + pix;
    #pragma unroll
    for (int ch = 0; ch < C; ++ch)
        ob[(size_t)ch * HW] *= inv;
}

extern "C" void kernel_launch(void* const* d_in, const int* in_sizes, int n_in,
                              void* d_out, int out_size, void* d_ws, size_t ws_size,
                              hipStream_t stream)
{
    const float* xyz  = (const float*)d_in[0];   // (BS, P, 3)
    const float* data = (const float*)d_in[1];   // (BS, C, P)

    float* out  = (float*)d_out;
    float* conf = out  + (size_t)BS * C * HW;
    float* viz  = conf + (size_t)BS * HW;

    const size_t acc_bytes = (size_t)BS * HW * C * sizeof(unsigned short);  // 64 MB

    if (ws_size >= acc_bytes) {
        unsigned short* acc = (unsigned short*)d_ws;
        (void)hipMemsetAsync(acc, 0, acc_bytes, stream);
        (void)hipMemsetAsync(conf, 0, (size_t)BS * HW * sizeof(float), stream);
        splat_scatter_t<<<BS * P / TP, 256, 0, stream>>>(xyz, data, acc, conf, viz);
        splat_transpose_norm<<<BS * HW / 64, 256, 0, stream>>>(acc, conf, out);
    } else {
        (void)hipMemsetAsync(d_out, 0, (size_t)(BS * C * HW + BS * HW) * sizeof(float), stream);
        splat_scatter_fb<<<(BS * P + 255) / 256, 256, 0, stream>>>(xyz, data, out, conf, viz);
        splat_norm_fb<<<(BS * HW + 255) / 256, 256, 0, stream>>>(out, conf);
    }
}